// Round 3
// baseline (523.601 us; speedup 1.0000x reference)
//
#include <hip/hip_runtime.h>
#include <stdint.h>

#define HEADS 16
#define NTOK 98
#define HD 32
#define SCALE_Q 0.17677669529663687f

typedef __attribute__((ext_vector_type(4))) float floatx4;
typedef __attribute__((ext_vector_type(8))) short shortx8;

__device__ __forceinline__ unsigned short f2bf(float f) {
  union { float f; unsigned u; } v; v.f = f;
  unsigned r = v.u + 0x7fffu + ((v.u >> 16) & 1u);
  return (unsigned short)(r >> 16);
}
__device__ __forceinline__ float bf2f(unsigned short s) {
  union { unsigned u; float f; } v; v.u = ((unsigned)s) << 16;
  return v.f;
}

__device__ __forceinline__ void gload_lds16(const void* g, void* l) {
  __builtin_amdgcn_global_load_lds(
      (const __attribute__((address_space(1))) unsigned int*)g,
      (__attribute__((address_space(3))) unsigned int*)l, 16, 0, 0);
}

// ---------------- prep kernels ----------------
__global__ void convert_x_kernel(const float* __restrict__ x,
                                 unsigned short* __restrict__ xbf) {
  int idx = blockIdx.x * 256 + threadIdx.x;  // one per 8 elems; 3,211,264 total
  const float4 f0 = *(const float4*)(x + (size_t)idx * 8);
  const float4 f1 = *(const float4*)(x + (size_t)idx * 8 + 4);
  union { ushort us[8]; uint4 u4; } pk;
  pk.us[0] = f2bf(f0.x); pk.us[1] = f2bf(f0.y);
  pk.us[2] = f2bf(f0.z); pk.us[3] = f2bf(f0.w);
  pk.us[4] = f2bf(f1.x); pk.us[5] = f2bf(f1.y);
  pk.us[6] = f2bf(f1.z); pk.us[7] = f2bf(f1.w);
  *(uint4*)(xbf + (size_t)idx * 8) = pk.u4;
}

__global__ void convert_w_kernel(const float* __restrict__ qkv_w,
                                 const float* __restrict__ proj_w,
                                 unsigned short* __restrict__ wq,
                                 unsigned short* __restrict__ wp) {
  int idx = blockIdx.x * 256 + threadIdx.x;
  if (idx < 1536 * 512) wq[idx] = f2bf(qkv_w[idx]);
  if (idx < 512 * 512) wp[idx] = f2bf(proj_w[idx]);
}

// Separable, fragment-ordered bias/mask tables (f32):
//   biasP[h][mt][lane][e]  (16*7*64*32 = 229,376 floats)
//   maskP[w][mt][lane][e]  (64*7*64*32 = 917,504 floats)
// e = nt*4 + r (pad to 32); i = mt*16 + (lane>>4)*4 + r; j = nt*16 + (lane&15).
// mask pad: j>=98 -> -1e30 (kills softmax), i>=98 -> 0 (row discarded).
__global__ void bmprep_kernel(const float* __restrict__ table,
                              const int* __restrict__ rel,
                              const float* __restrict__ mask,
                              float* __restrict__ biasP,
                              float* __restrict__ maskP) {
  int idx = blockIdx.x * 256 + threadIdx.x;
  if (idx < 229376) {
    int e = idx & 31, lane = (idx >> 5) & 63;
    int rest = idx >> 11;          // h*7 + mt
    int mt = rest % 7, h = rest / 7;
    int nt = e >> 2, r = e & 3;
    int i = mt * 16 + ((lane >> 4) << 2) + r;
    int j = (nt << 4) + (lane & 15);
    float v = 0.f;
    if (nt < 7 && i < NTOK && j < NTOK) v = table[rel[i * NTOK + j] * HEADS + h];
    biasP[idx] = v;
  } else {
    int t = idx - 229376;
    int e = t & 31, lane = (t >> 5) & 63;
    int rest = t >> 11;            // w*7 + mt
    int mt = rest % 7, wdx = rest / 7;
    int nt = e >> 2, r = e & 3;
    int i = mt * 16 + ((lane >> 4) << 2) + r;
    int j = (nt << 4) + (lane & 15);
    float v;
    if (nt >= 7) v = 0.f;
    else if (j >= NTOK) v = -1e30f;
    else if (i >= NTOK) v = 0.f;
    else v = mask[wdx * (NTOK * NTOK) + i * NTOK + j];
    maskP[t] = v;
  }
}

// ---------------- QKV GEMM: C[50176,1536] = xbf[50176,512] @ qkv_w[1536,512]^T ----------------
// 128x256 tile, BK=32, 512 threads (8 waves, 2x4, each 64x64).
// 3-buffer pipeline, counted vmcnt(3) (drain-0 only on last iter), one raw
// s_barrier per K-step; seg-XOR swizzle (pre-swizzled global source + swizzled
// ds_read) keeps reads conflict-free with linear gload_lds destinations.
__global__ __launch_bounds__(512, 2)
void qkv_gemm_kernel(const unsigned short* __restrict__ xbf,
                     const unsigned short* __restrict__ wbf,
                     const float* __restrict__ qkv_b,
                     unsigned short* __restrict__ q_out,
                     unsigned short* __restrict__ k_out,
                     unsigned short* __restrict__ v_out) {
  __shared__ unsigned short As[3][128 * 32];
  __shared__ unsigned short Bs[3][256 * 32];
  const int tid = threadIdx.x;
  const int wave = tid >> 6, lane = tid & 63;
  const int m0 = blockIdx.x * 128, n0 = blockIdx.y * 256;
  const int wm = wave & 1, wn = wave >> 1;
  const int ln15 = lane & 15, qd = lane >> 4;
  const int bl_r = lane >> 2, bl_s = lane & 3;

  const int sg_st = bl_s ^ ((bl_r >> 1) & 3);       // staging source seg
  const int swz_rd = (qd ^ ((ln15 >> 1) & 3)) * 8;  // read seg offset (shorts)

  const unsigned short* aG = xbf + (size_t)(m0 + wave * 16 + bl_r) * 512 + sg_st * 8;
  const unsigned short* bG0 = wbf + (size_t)(n0 + wave * 32 + bl_r) * 512 + sg_st * 8;
  const unsigned short* bG1 = wbf + (size_t)(n0 + wave * 32 + 16 + bl_r) * 512 + sg_st * 8;

#define QSTAGE(bufi, kk)                                                        \
  do {                                                                          \
    gload_lds16((const void*)(aG + (kk)), (void*)&As[bufi][wave * 512]);        \
    gload_lds16((const void*)(bG0 + (kk)), (void*)&Bs[bufi][wave * 1024]);      \
    gload_lds16((const void*)(bG1 + (kk)), (void*)&Bs[bufi][wave * 1024 + 512]);\
  } while (0)

  QSTAGE(0, 0);
  QSTAGE(1, 32);

  floatx4 acc[4][4] = {};
#pragma unroll
  for (int it = 0; it < 16; ++it) {
    if (it == 15) asm volatile("s_waitcnt vmcnt(0)" ::: "memory");
    else          asm volatile("s_waitcnt vmcnt(3)" ::: "memory");
    __builtin_amdgcn_sched_barrier(0);
    __builtin_amdgcn_s_barrier();
    __builtin_amdgcn_sched_barrier(0);
    if (it + 2 < 16) QSTAGE((it + 2) % 3, (it + 2) * 32);
    const unsigned short* Ab = As[it % 3];
    const unsigned short* Bb = Bs[it % 3];
    shortx8 afrag[4], bfrag[4];
#pragma unroll
    for (int mt = 0; mt < 4; ++mt)
      afrag[mt] = *(const shortx8*)&Ab[(wm * 64 + mt * 16 + ln15) * 32 + swz_rd];
#pragma unroll
    for (int nt = 0; nt < 4; ++nt)
      bfrag[nt] = *(const shortx8*)&Bb[(wn * 64 + nt * 16 + ln15) * 32 + swz_rd];
#pragma unroll
    for (int mt = 0; mt < 4; ++mt)
#pragma unroll
      for (int nt = 0; nt < 4; ++nt)
        acc[mt][nt] = __builtin_amdgcn_mfma_f32_16x16x32_bf16(
            afrag[mt], bfrag[nt], acc[mt][nt], 0, 0, 0);
  }
#undef QSTAGE

  // epilogue: + qkv_b, scale q, scatter to [B,H,98,32] bf16
#pragma unroll
  for (int mt = 0; mt < 4; ++mt) {
#pragma unroll
    for (int r = 0; r < 4; ++r) {
      int grow = m0 + wm * 64 + mt * 16 + qd * 4 + r;
      unsigned b = (unsigned)grow / 98u;
      unsigned i = (unsigned)grow - b * 98u;
#pragma unroll
      for (int nt = 0; nt < 4; ++nt) {
        int col = n0 + wn * 64 + nt * 16 + ln15;
        float val = acc[mt][nt][r] + qkv_b[col];
        int which = col >> 9;
        int h = (col >> 5) & 15;
        int d = col & 31;
        size_t oidx = ((size_t)(b * 16 + h) * 98 + i) * 32 + d;
        if (which == 0)      q_out[oidx] = f2bf(val * SCALE_Q);
        else if (which == 1) k_out[oidx] = f2bf(val);
        else                 v_out[oidx] = f2bf(val);
      }
    }
  }
}

// ---------------- attention: one block per (b,h) ----------------
__global__ __launch_bounds__(256, 4)
void attn_kernel(const unsigned short* __restrict__ qg,
                 const unsigned short* __restrict__ kg,
                 const unsigned short* __restrict__ vg,
                 const float* __restrict__ biasP,
                 const float* __restrict__ maskP,
                 unsigned short* __restrict__ outg) {
  __shared__ unsigned short Vt[32 * 136];
  __shared__ unsigned short Ps[4][16 * 40];  // per-wave private P chunk
  const int tid = threadIdx.x;
  const int bh = blockIdx.x;
  const int b = bh >> 4, h = bh & 15, w = b & 63;
  const size_t base = (size_t)bh * (NTOK * HD);
  const int wave = tid >> 6, lane = tid & 63;
  const int ln15 = lane & 15, qd = lane >> 4;

  // zero Vt (pad cols 98..135 must be finite-zero for the PV MFMA)
  for (int idx = tid; idx < 544; idx += 256)
    ((uint4*)Vt)[idx] = make_uint4(0, 0, 0, 0);
  __syncthreads();
  // transpose V into Vt[d][j]; seg-staggered write order spreads the 8-row
  // seg groups across bank quadrants (was 8-way conflicted)
  for (int t = tid; t < 392; t += 256) {
    int i = t >> 2, seg = t & 3;
    union { uint4 u4; unsigned short us[8]; } u;
    u.u4 = *(const uint4*)(vg + base + i * 32 + seg * 8);
    int d0 = seg * 8;
#pragma unroll
    for (int e0 = 0; e0 < 8; ++e0) {
      int e = (e0 + seg * 2) & 7;
      Vt[(d0 + e) * 136 + i] = u.us[e];
    }
  }
  __syncthreads();

  floatx4 oacc[2];
#pragma unroll
  for (int mslot = 0; mslot < 2; ++mslot) {
    int mt = wave + mslot * 4;
    if (mt >= 7) break;  // wave 3 has one M-tile
    // coalesced fragment-ordered bias+mask (f32, L2-resident); loads issued
    // before the MFMA loop so latency hides under QK^T
    const floatx4* bP = (const floatx4*)(biasP + (((size_t)h * 7 + mt) * 64 + lane) * 32);
    const floatx4* mP = (const floatx4*)(maskP + (((size_t)w * 7 + mt) * 64 + lane) * 32);
    floatx4 bb[7];
#pragma unroll
    for (int nt = 0; nt < 7; ++nt) bb[nt] = bP[nt] + mP[nt];

    shortx8 af = *(const shortx8*)(qg + base + (mt * 16 + ln15) * 32 + qd * 8);
    floatx4 sacc[7];
#pragma unroll
    for (int nt = 0; nt < 7; ++nt) {
      shortx8 bf = *(const shortx8*)(kg + base + (nt * 16 + ln15) * 32 + qd * 8);
      floatx4 z = {};
      sacc[nt] = __builtin_amdgcn_mfma_f32_16x16x32_bf16(af, bf, z, 0, 0, 0);
    }
#pragma unroll
    for (int nt = 0; nt < 7; ++nt) sacc[nt] += bb[nt];

    float linv[4];
#pragma unroll
    for (int r = 0; r < 4; ++r) {
      float mx = sacc[0][r];
#pragma unroll
      for (int nt = 1; nt < 7; ++nt) mx = fmaxf(mx, sacc[nt][r]);
#pragma unroll
      for (int off = 1; off < 16; off <<= 1)
        mx = fmaxf(mx, __shfl_xor(mx, off, 64));
      float sum = 0.f;
#pragma unroll
      for (int nt = 0; nt < 7; ++nt) {
        float p = __expf(sacc[nt][r] - mx);
        sacc[nt][r] = p;
        sum += p;
      }
#pragma unroll
      for (int off = 1; off < 16; off <<= 1) sum += __shfl_xor(sum, off, 64);
      linv[r] = 1.0f / sum;
    }
    // chunked PV: write 16x32 P chunk (wave-private), read A-frag, 2 MFMA
    oacc[0] = (floatx4){};
    oacc[1] = (floatx4){};
#pragma unroll
    for (int ks = 0; ks < 4; ++ks) {
#pragma unroll
      for (int nt2 = 0; nt2 < 2; ++nt2) {
        int nt = ks * 2 + nt2;
#pragma unroll
        for (int r = 0; r < 4; ++r)
          Ps[wave][(qd * 4 + r) * 40 + nt2 * 16 + ln15] = f2bf(sacc[nt][r]);
      }
      shortx8 ap = *(const shortx8*)&Ps[wave][ln15 * 40 + qd * 8];
      shortx8 bv0 = *(const shortx8*)&Vt[ln15 * 136 + ks * 32 + qd * 8];
      shortx8 bv1 = *(const shortx8*)&Vt[(16 + ln15) * 136 + ks * 32 + qd * 8];
      oacc[0] = __builtin_amdgcn_mfma_f32_16x16x32_bf16(ap, bv0, oacc[0], 0, 0, 0);
      oacc[1] = __builtin_amdgcn_mfma_f32_16x16x32_bf16(ap, bv1, oacc[1], 0, 0, 0);
    }
    // store this M-tile to [b*98+i][512] at col h*32
#pragma unroll
    for (int r = 0; r < 4; ++r) {
      int i = mt * 16 + qd * 4 + r;
      if (i < NTOK) {
        size_t ob = ((size_t)b * NTOK + i) * 512 + h * 32;
#pragma unroll
        for (int vt = 0; vt < 2; ++vt)
          outg[ob + vt * 16 + ln15] = f2bf(oacc[vt][r] * linv[r]);
      }
    }
  }
}

// ---------------- proj GEMM: out[50176,512] = attn[50176,512] @ proj_w[512,512]^T + b ----------------
// Same structure as qkv_gemm: 128x256 tile, 8 waves, 3-buffer counted vmcnt.
__global__ __launch_bounds__(512, 2)
void proj_gemm_kernel(const unsigned short* __restrict__ a,
                      const unsigned short* __restrict__ wbf,
                      const float* __restrict__ proj_b,
                      float* __restrict__ out) {
  __shared__ unsigned short As[3][128 * 32];
  __shared__ unsigned short Bs[3][256 * 32];
  const int tid = threadIdx.x;
  const int wave = tid >> 6, lane = tid & 63;
  const int m0 = blockIdx.x * 128, n0 = blockIdx.y * 256;
  const int wm = wave & 1, wn = wave >> 1;
  const int ln15 = lane & 15, qd = lane >> 4;
  const int bl_r = lane >> 2, bl_s = lane & 3;

  const int sg_st = bl_s ^ ((bl_r >> 1) & 3);
  const int swz_rd = (qd ^ ((ln15 >> 1) & 3)) * 8;

  const unsigned short* aG = a + (size_t)(m0 + wave * 16 + bl_r) * 512 + sg_st * 8;
  const unsigned short* bG0 = wbf + (size_t)(n0 + wave * 32 + bl_r) * 512 + sg_st * 8;
  const unsigned short* bG1 = wbf + (size_t)(n0 + wave * 32 + 16 + bl_r) * 512 + sg_st * 8;

#define PSTAGE(bufi, kk)                                                        \
  do {                                                                          \
    gload_lds16((const void*)(aG + (kk)), (void*)&As[bufi][wave * 512]);        \
    gload_lds16((const void*)(bG0 + (kk)), (void*)&Bs[bufi][wave * 1024]);      \
    gload_lds16((const void*)(bG1 + (kk)), (void*)&Bs[bufi][wave * 1024 + 512]);\
  } while (0)

  PSTAGE(0, 0);
  PSTAGE(1, 32);

  floatx4 acc[4][4] = {};
#pragma unroll
  for (int it = 0; it < 16; ++it) {
    if (it == 15) asm volatile("s_waitcnt vmcnt(0)" ::: "memory");
    else          asm volatile("s_waitcnt vmcnt(3)" ::: "memory");
    __builtin_amdgcn_sched_barrier(0);
    __builtin_amdgcn_s_barrier();
    __builtin_amdgcn_sched_barrier(0);
    if (it + 2 < 16) PSTAGE((it + 2) % 3, (it + 2) * 32);
    const unsigned short* Ab = As[it % 3];
    const unsigned short* Bb = Bs[it % 3];
    shortx8 afrag[4], bfrag[4];
#pragma unroll
    for (int mt = 0; mt < 4; ++mt)
      afrag[mt] = *(const shortx8*)&Ab[(wm * 64 + mt * 16 + ln15) * 32 + swz_rd];
#pragma unroll
    for (int nt = 0; nt < 4; ++nt)
      bfrag[nt] = *(const shortx8*)&Bb[(wn * 64 + nt * 16 + ln15) * 32 + swz_rd];
#pragma unroll
    for (int mt = 0; mt < 4; ++mt)
#pragma unroll
      for (int nt = 0; nt < 4; ++nt)
        acc[mt][nt] = __builtin_amdgcn_mfma_f32_16x16x32_bf16(
            afrag[mt], bfrag[nt], acc[mt][nt], 0, 0, 0);
  }
#undef PSTAGE

#pragma unroll
  for (int mt = 0; mt < 4; ++mt) {
#pragma unroll
    for (int r = 0; r < 4; ++r) {
      int grow = m0 + wm * 64 + mt * 16 + qd * 4 + r;
#pragma unroll
      for (int nt = 0; nt < 4; ++nt) {
        int col = n0 + wn * 64 + nt * 16 + ln15;
        out[(size_t)grow * 512 + col] = acc[mt][nt][r] + proj_b[col];
      }
    }
  }
}

// ---------------- launch ----------------
extern "C" void kernel_launch(void* const* d_in, const int* in_sizes, int n_in,
                              void* d_out, int out_size, void* d_ws, size_t ws_size,
                              hipStream_t stream) {
  const float* x          = (const float*)d_in[0];
  const float* mask       = (const float*)d_in[1];
  const float* qkv_w      = (const float*)d_in[2];
  const float* qkv_b      = (const float*)d_in[3];
  const float* proj_w     = (const float*)d_in[4];
  const float* proj_b     = (const float*)d_in[5];
  const float* bias_table = (const float*)d_in[6];
  const int*   rel_index  = (const int*)d_in[7];
  float* out = (float*)d_out;

  char* ws = (char*)d_ws;
  unsigned short* ws_qkvw  = (unsigned short*)(ws + 0);           // 1,572,864
  unsigned short* ws_projw = (unsigned short*)(ws + 1572864);     //   524,288
  float*          ws_biasP = (float*)(ws + 2097152);              //   917,504
  float*          ws_maskP = (float*)(ws + 3014656);              // 3,670,016
  unsigned short* ws_q     = (unsigned short*)(ws + 6684672);     // 51,380,224
  unsigned short* ws_k     = (unsigned short*)(ws + 58064896);
  unsigned short* ws_v     = (unsigned short*)(ws + 109445120);
  unsigned short* ws_attn  = (unsigned short*)(ws + 160825344);   // end 212,205,568
  unsigned short* ws_xbf   = ws_attn;  // aliased: xbf dead before attn writes

  hipLaunchKernelGGL(convert_x_kernel, dim3(12544), dim3(256), 0, stream,
                     x, ws_xbf);
  hipLaunchKernelGGL(convert_w_kernel, dim3(3072), dim3(256), 0, stream,
                     qkv_w, proj_w, ws_qkvw, ws_projw);
  hipLaunchKernelGGL(bmprep_kernel, dim3(4480), dim3(256), 0, stream,
                     bias_table, rel_index, mask, ws_biasP, ws_maskP);
  hipLaunchKernelGGL(qkv_gemm_kernel, dim3(392, 6), dim3(512), 0, stream,
                     ws_xbf, ws_qkvw, qkv_b, ws_q, ws_k, ws_v);
  hipLaunchKernelGGL(attn_kernel, dim3(8192), dim3(256), 0, stream,
                     ws_q, ws_k, ws_v, ws_biasP, ws_maskP, ws_attn);
  hipLaunchKernelGGL(proj_gemm_kernel, dim3(392, 2), dim3(512), 0, stream,
                     ws_attn, ws_projw, proj_b, out);
}

// Round 4
// 452.843 us; speedup vs baseline: 1.1563x; 1.1563x over previous
//
#include <hip/hip_runtime.h>
#include <stdint.h>

#define HEADS 16
#define NTOK 98
#define HD 32
#define SCALE_Q 0.17677669529663687f

typedef __attribute__((ext_vector_type(4))) float floatx4;
typedef __attribute__((ext_vector_type(8))) short shortx8;

__device__ __forceinline__ unsigned short f2bf(float f) {
  union { float f; unsigned u; } v; v.f = f;
  unsigned r = v.u + 0x7fffu + ((v.u >> 16) & 1u);
  return (unsigned short)(r >> 16);
}
__device__ __forceinline__ float bf2f(unsigned short s) {
  union { unsigned u; float f; } v; v.u = ((unsigned)s) << 16;
  return v.f;
}

__device__ __forceinline__ void gload_lds16(const void* g, void* l) {
  __builtin_amdgcn_global_load_lds(
      (const __attribute__((address_space(1))) unsigned int*)g,
      (__attribute__((address_space(3))) unsigned int*)l, 16, 0, 0);
}

// ---------------- prep kernels ----------------
__global__ void convert_x_kernel(const float* __restrict__ x,
                                 unsigned short* __restrict__ xbf) {
  int idx = blockIdx.x * 256 + threadIdx.x;  // one per 8 elems; 3,211,264 total
  const float4 f0 = *(const float4*)(x + (size_t)idx * 8);
  const float4 f1 = *(const float4*)(x + (size_t)idx * 8 + 4);
  union { ushort us[8]; uint4 u4; } pk;
  pk.us[0] = f2bf(f0.x); pk.us[1] = f2bf(f0.y);
  pk.us[2] = f2bf(f0.z); pk.us[3] = f2bf(f0.w);
  pk.us[4] = f2bf(f1.x); pk.us[5] = f2bf(f1.y);
  pk.us[6] = f2bf(f1.z); pk.us[7] = f2bf(f1.w);
  *(uint4*)(xbf + (size_t)idx * 8) = pk.u4;
}

__global__ void convert_w_kernel(const float* __restrict__ qkv_w,
                                 const float* __restrict__ proj_w,
                                 unsigned short* __restrict__ wq,
                                 unsigned short* __restrict__ wp) {
  int idx = blockIdx.x * 256 + threadIdx.x;
  if (idx < 1536 * 512) wq[idx] = f2bf(qkv_w[idx]);
  if (idx < 512 * 512) wp[idx] = f2bf(proj_w[idx]);
}

// Separable, fragment-ordered bias/mask tables in BF16 (L2-resident: 2.3 MB):
//   biasF[h][mt][lane][e]  16*7*64*32 shorts = 458,752 B
//   maskF[w][mt][lane][e]  64*7*64*32 shorts = 1,835,008 B
// e = nt*4 + r (padded to 32); i = mt*16 + (lane>>4)*4 + r; j = nt*16 + (lane&15)
// mask pad: j>=98 -> -1e30 (kills softmax); rows i>=98 are discarded at store.
__global__ void bmprep_kernel(const float* __restrict__ table,
                              const int* __restrict__ rel,
                              const float* __restrict__ mask,
                              unsigned short* __restrict__ biasF,
                              unsigned short* __restrict__ maskF) {
  int idx = blockIdx.x * 256 + threadIdx.x;  // 1,146,880 total
  if (idx < 229376) {
    int e = idx & 31, lane = (idx >> 5) & 63;
    int rest = idx >> 11;          // h*7 + mt
    int mt = rest % 7, h = rest / 7;
    int nt = e >> 2, r = e & 3;
    int i = mt * 16 + ((lane >> 4) << 2) + r;
    int j = (nt << 4) + (lane & 15);
    int ii = i < NTOK ? i : 97, jj = j < NTOK ? j : 97;
    float v = (nt < 7) ? table[rel[ii * NTOK + jj] * HEADS + h] : 0.f;
    biasF[idx] = f2bf(v);
  } else {
    int t = idx - 229376;
    int e = t & 31, lane = (t >> 5) & 63;
    int rest = t >> 11;            // w*7 + mt
    int mt = rest % 7, wdx = rest / 7;
    int nt = e >> 2, r = e & 3;
    int i = mt * 16 + ((lane >> 4) << 2) + r;
    int j = (nt << 4) + (lane & 15);
    float v;
    if (nt >= 7) v = 0.f;
    else if (j >= NTOK) v = -1e30f;
    else {
      int ii = i < NTOK ? i : 97;
      v = mask[wdx * (NTOK * NTOK) + ii * NTOK + j];
    }
    maskF[t] = f2bf(v);
  }
}

// ---------------- QKV GEMM: C[50176,1536] = xbf[50176,512] @ qkv_w[1536,512]^T ----------------
// 128x256 tile, BK=32, 512 threads (8 waves, 2x4, each 64x64).
// 3-buffer pipeline, counted vmcnt(3) (drain-0 only on last iter), one raw
// s_barrier per K-step; seg-XOR swizzle (pre-swizzled global source + swizzled
// ds_read) keeps reads conflict-free with linear gload_lds destinations.
__global__ __launch_bounds__(512, 2)
void qkv_gemm_kernel(const unsigned short* __restrict__ xbf,
                     const unsigned short* __restrict__ wbf,
                     const float* __restrict__ qkv_b,
                     unsigned short* __restrict__ q_out,
                     unsigned short* __restrict__ k_out,
                     unsigned short* __restrict__ v_out) {
  __shared__ unsigned short As[3][128 * 32];
  __shared__ unsigned short Bs[3][256 * 32];
  const int tid = threadIdx.x;
  const int wave = tid >> 6, lane = tid & 63;
  const int m0 = blockIdx.x * 128, n0 = blockIdx.y * 256;
  const int wm = wave & 1, wn = wave >> 1;
  const int ln15 = lane & 15, qd = lane >> 4;
  const int bl_r = lane >> 2, bl_s = lane & 3;

  const int sg_st = bl_s ^ ((bl_r >> 1) & 3);       // staging source seg
  const int swz_rd = (qd ^ ((ln15 >> 1) & 3)) * 8;  // read seg offset (shorts)

  const unsigned short* aG = xbf + (size_t)(m0 + wave * 16 + bl_r) * 512 + sg_st * 8;
  const unsigned short* bG0 = wbf + (size_t)(n0 + wave * 32 + bl_r) * 512 + sg_st * 8;
  const unsigned short* bG1 = wbf + (size_t)(n0 + wave * 32 + 16 + bl_r) * 512 + sg_st * 8;

#define QSTAGE(bufi, kk)                                                        \
  do {                                                                          \
    gload_lds16((const void*)(aG + (kk)), (void*)&As[bufi][wave * 512]);        \
    gload_lds16((const void*)(bG0 + (kk)), (void*)&Bs[bufi][wave * 1024]);      \
    gload_lds16((const void*)(bG1 + (kk)), (void*)&Bs[bufi][wave * 1024 + 512]);\
  } while (0)

  QSTAGE(0, 0);
  QSTAGE(1, 32);

  floatx4 acc[4][4] = {};
#pragma unroll
  for (int it = 0; it < 16; ++it) {
    if (it == 15) asm volatile("s_waitcnt vmcnt(0)" ::: "memory");
    else          asm volatile("s_waitcnt vmcnt(3)" ::: "memory");
    __builtin_amdgcn_sched_barrier(0);
    __builtin_amdgcn_s_barrier();
    __builtin_amdgcn_sched_barrier(0);
    if (it + 2 < 16) QSTAGE((it + 2) % 3, (it + 2) * 32);
    const unsigned short* Ab = As[it % 3];
    const unsigned short* Bb = Bs[it % 3];
    shortx8 afrag[4], bfrag[4];
#pragma unroll
    for (int mt = 0; mt < 4; ++mt)
      afrag[mt] = *(const shortx8*)&Ab[(wm * 64 + mt * 16 + ln15) * 32 + swz_rd];
#pragma unroll
    for (int nt = 0; nt < 4; ++nt)
      bfrag[nt] = *(const shortx8*)&Bb[(wn * 64 + nt * 16 + ln15) * 32 + swz_rd];
#pragma unroll
    for (int mt = 0; mt < 4; ++mt)
#pragma unroll
      for (int nt = 0; nt < 4; ++nt)
        acc[mt][nt] = __builtin_amdgcn_mfma_f32_16x16x32_bf16(
            afrag[mt], bfrag[nt], acc[mt][nt], 0, 0, 0);
  }
#undef QSTAGE

  // epilogue: + qkv_b, scale q, scatter to [B,H,98,32] bf16
#pragma unroll
  for (int mt = 0; mt < 4; ++mt) {
#pragma unroll
    for (int r = 0; r < 4; ++r) {
      int grow = m0 + wm * 64 + mt * 16 + qd * 4 + r;
      unsigned b = (unsigned)grow / 98u;
      unsigned i = (unsigned)grow - b * 98u;
#pragma unroll
      for (int nt = 0; nt < 4; ++nt) {
        int col = n0 + wn * 64 + nt * 16 + ln15;
        float val = acc[mt][nt][r] + qkv_b[col];
        int which = col >> 9;
        int h = (col >> 5) & 15;
        int d = col & 31;
        size_t oidx = ((size_t)(b * 16 + h) * 98 + i) * 32 + d;
        if (which == 0)      q_out[oidx] = f2bf(val * SCALE_Q);
        else if (which == 1) k_out[oidx] = f2bf(val);
        else                 v_out[oidx] = f2bf(val);
      }
    }
  }
}

// ---------------- attention: one block per (b,h), 7 waves, one m-tile per wave ----------------
__global__ __launch_bounds__(448, 6)
void attn_kernel(const unsigned short* __restrict__ qg,
                 const unsigned short* __restrict__ kg,
                 const unsigned short* __restrict__ vg,
                 const unsigned short* __restrict__ biasF,
                 const unsigned short* __restrict__ maskF,
                 unsigned short* __restrict__ outg) {
  __shared__ __align__(16) unsigned short Vt[32 * 136];   // 8704 B
  __shared__ __align__(16) unsigned short Ps[7][1928];    // 16 rows x 120 + 8 pad, per wave
  const int tid = threadIdx.x;
  const int bh = blockIdx.x;
  const int b = bh >> 4, h = bh & 15, w = b & 63;
  const size_t base = (size_t)bh * (NTOK * HD);
  const int wave = tid >> 6, lane = tid & 63;   // wave = m-tile (0..6)
  const int ln15 = lane & 15, qd = lane >> 4;

  // zero Vt (pad cols 98..135) and Ps (pad cols 112..119 + tail) — all MFMA
  // slack reads must be finite zeros
  for (int idx = tid; idx < 544; idx += 448)
    ((uint4*)Vt)[idx] = make_uint4(0, 0, 0, 0);
  for (int idx = tid; idx < 1687; idx += 448)
    ((uint4*)Ps)[idx] = make_uint4(0, 0, 0, 0);
  __syncthreads();
  // transpose V into Vt[d][j]; seg-staggered write order spreads the 8-row
  // seg groups across bank quadrants
  for (int t = tid; t < 392; t += 448) {
    int i = t >> 2, seg = t & 3;
    union { uint4 u4; unsigned short us[8]; } u;
    u.u4 = *(const uint4*)(vg + base + i * 32 + seg * 8);
    int d0 = seg * 8;
#pragma unroll
    for (int e0 = 0; e0 < 8; ++e0) {
      int e = (e0 + seg * 2) & 7;
      Vt[(d0 + e) * 136 + i] = u.us[e];
    }
  }
  __syncthreads();

  const int mt = wave;
  // bf16 fragment-ordered bias/mask chunks (L2-resident, 8 x 16B per lane);
  // issued before QK^T so latency hides under the MFMAs
  const shortx8* bB = (const shortx8*)(biasF + (((size_t)h * 7 + mt) * 64 + lane) * 32);
  const shortx8* mB = (const shortx8*)(maskF + (((size_t)w * 7 + mt) * 64 + lane) * 32);
  shortx8 bias_c[4], mask_c[4];
#pragma unroll
  for (int c = 0; c < 4; ++c) { bias_c[c] = bB[c]; mask_c[c] = mB[c]; }

  shortx8 af = *(const shortx8*)(qg + base + (mt * 16 + ln15) * 32 + qd * 8);
  floatx4 sacc[7];
#pragma unroll
  for (int nt = 0; nt < 7; ++nt) {
    shortx8 bf = *(const shortx8*)(kg + base + (nt * 16 + ln15) * 32 + qd * 8);
    floatx4 z = {};
    sacc[nt] = __builtin_amdgcn_mfma_f32_16x16x32_bf16(af, bf, z, 0, 0, 0);
  }
  // add bias+mask (frees the chunks before softmax)
#pragma unroll
  for (int nt = 0; nt < 7; ++nt)
#pragma unroll
    for (int r = 0; r < 4; ++r) {
      int ee = nt * 4 + r, c = ee >> 3, el = ee & 7;
      sacc[nt][r] += bf2f((unsigned short)bias_c[c][el]) +
                     bf2f((unsigned short)mask_c[c][el]);
    }

  float linv[4];
#pragma unroll
  for (int r = 0; r < 4; ++r) {
    float mx = sacc[0][r];
#pragma unroll
    for (int nt = 1; nt < 7; ++nt) mx = fmaxf(mx, sacc[nt][r]);
#pragma unroll
    for (int off = 1; off < 16; off <<= 1)
      mx = fmaxf(mx, __shfl_xor(mx, off, 64));
    float sum = 0.f;
#pragma unroll
    for (int nt = 0; nt < 7; ++nt) {
      float p = __expf(sacc[nt][r] - mx);
      sacc[nt][r] = p;
      sum += p;
    }
#pragma unroll
    for (int off = 1; off < 16; off <<= 1) sum += __shfl_xor(sum, off, 64);
    linv[r] = 1.0f / sum;
  }

  // store full 16x112 P once (stride 120 shorts: 2-way max bank aliasing),
  // then 4 pipelined k-slice MFMAs — no per-slice write->read serialization
  unsigned short* Pw = Ps[wave];
#pragma unroll
  for (int nt = 0; nt < 7; ++nt)
#pragma unroll
    for (int r = 0; r < 4; ++r)
      Pw[(qd * 4 + r) * 120 + nt * 16 + ln15] = f2bf(sacc[nt][r]);

  floatx4 o0 = {}, o1 = {};
#pragma unroll
  for (int ks = 0; ks < 4; ++ks) {
    shortx8 ap = *(const shortx8*)&Pw[ln15 * 120 + ks * 32 + qd * 8];
    shortx8 bv0 = *(const shortx8*)&Vt[ln15 * 136 + ks * 32 + qd * 8];
    shortx8 bv1 = *(const shortx8*)&Vt[(16 + ln15) * 136 + ks * 32 + qd * 8];
    o0 = __builtin_amdgcn_mfma_f32_16x16x32_bf16(ap, bv0, o0, 0, 0, 0);
    o1 = __builtin_amdgcn_mfma_f32_16x16x32_bf16(ap, bv1, o1, 0, 0, 0);
  }
  // store this m-tile to [b*98+i][512] at col h*32
#pragma unroll
  for (int r = 0; r < 4; ++r) {
    int i = mt * 16 + qd * 4 + r;
    if (i < NTOK) {
      size_t ob = ((size_t)b * NTOK + i) * 512 + h * 32;
      outg[ob + ln15] = f2bf(o0[r] * linv[r]);
      outg[ob + 16 + ln15] = f2bf(o1[r] * linv[r]);
    }
  }
}

// ---------------- proj GEMM: out[50176,512] = attn[50176,512] @ proj_w[512,512]^T + b ----------------
// Same structure as qkv_gemm: 128x256 tile, 8 waves, 3-buffer counted vmcnt.
__global__ __launch_bounds__(512, 2)
void proj_gemm_kernel(const unsigned short* __restrict__ a,
                      const unsigned short* __restrict__ wbf,
                      const float* __restrict__ proj_b,
                      float* __restrict__ out) {
  __shared__ unsigned short As[3][128 * 32];
  __shared__ unsigned short Bs[3][256 * 32];
  const int tid = threadIdx.x;
  const int wave = tid >> 6, lane = tid & 63;
  const int m0 = blockIdx.x * 128, n0 = blockIdx.y * 256;
  const int wm = wave & 1, wn = wave >> 1;
  const int ln15 = lane & 15, qd = lane >> 4;
  const int bl_r = lane >> 2, bl_s = lane & 3;

  const int sg_st = bl_s ^ ((bl_r >> 1) & 3);
  const int swz_rd = (qd ^ ((ln15 >> 1) & 3)) * 8;

  const unsigned short* aG = a + (size_t)(m0 + wave * 16 + bl_r) * 512 + sg_st * 8;
  const unsigned short* bG0 = wbf + (size_t)(n0 + wave * 32 + bl_r) * 512 + sg_st * 8;
  const unsigned short* bG1 = wbf + (size_t)(n0 + wave * 32 + 16 + bl_r) * 512 + sg_st * 8;

#define PSTAGE(bufi, kk)                                                        \
  do {                                                                          \
    gload_lds16((const void*)(aG + (kk)), (void*)&As[bufi][wave * 512]);        \
    gload_lds16((const void*)(bG0 + (kk)), (void*)&Bs[bufi][wave * 1024]);      \
    gload_lds16((const void*)(bG1 + (kk)), (void*)&Bs[bufi][wave * 1024 + 512]);\
  } while (0)

  PSTAGE(0, 0);
  PSTAGE(1, 32);

  floatx4 acc[4][4] = {};
#pragma unroll
  for (int it = 0; it < 16; ++it) {
    if (it == 15) asm volatile("s_waitcnt vmcnt(0)" ::: "memory");
    else          asm volatile("s_waitcnt vmcnt(3)" ::: "memory");
    __builtin_amdgcn_sched_barrier(0);
    __builtin_amdgcn_s_barrier();
    __builtin_amdgcn_sched_barrier(0);
    if (it + 2 < 16) PSTAGE((it + 2) % 3, (it + 2) * 32);
    const unsigned short* Ab = As[it % 3];
    const unsigned short* Bb = Bs[it % 3];
    shortx8 afrag[4], bfrag[4];
#pragma unroll
    for (int mt = 0; mt < 4; ++mt)
      afrag[mt] = *(const shortx8*)&Ab[(wm * 64 + mt * 16 + ln15) * 32 + swz_rd];
#pragma unroll
    for (int nt = 0; nt < 4; ++nt)
      bfrag[nt] = *(const shortx8*)&Bb[(wn * 64 + nt * 16 + ln15) * 32 + swz_rd];
#pragma unroll
    for (int mt = 0; mt < 4; ++mt)
#pragma unroll
      for (int nt = 0; nt < 4; ++nt)
        acc[mt][nt] = __builtin_amdgcn_mfma_f32_16x16x32_bf16(
            afrag[mt], bfrag[nt], acc[mt][nt], 0, 0, 0);
  }
#undef PSTAGE

#pragma unroll
  for (int mt = 0; mt < 4; ++mt) {
#pragma unroll
    for (int r = 0; r < 4; ++r) {
      int grow = m0 + wm * 64 + mt * 16 + qd * 4 + r;
#pragma unroll
      for (int nt = 0; nt < 4; ++nt) {
        int col = n0 + wn * 64 + nt * 16 + ln15;
        out[(size_t)grow * 512 + col] = acc[mt][nt][r] + proj_b[col];
      }
    }
  }
}

// ---------------- launch ----------------
extern "C" void kernel_launch(void* const* d_in, const int* in_sizes, int n_in,
                              void* d_out, int out_size, void* d_ws, size_t ws_size,
                              hipStream_t stream) {
  const float* x          = (const float*)d_in[0];
  const float* mask       = (const float*)d_in[1];
  const float* qkv_w      = (const float*)d_in[2];
  const float* qkv_b      = (const float*)d_in[3];
  const float* proj_w     = (const float*)d_in[4];
  const float* proj_b     = (const float*)d_in[5];
  const float* bias_table = (const float*)d_in[6];
  const int*   rel_index  = (const int*)d_in[7];
  float* out = (float*)d_out;

  char* ws = (char*)d_ws;
  unsigned short* ws_qkvw  = (unsigned short*)(ws + 0);           // 1,572,864
  unsigned short* ws_projw = (unsigned short*)(ws + 1572864);     //   524,288
  unsigned short* ws_biasF = (unsigned short*)(ws + 2097152);     //   458,752
  unsigned short* ws_maskF = (unsigned short*)(ws + 2555904);     // 1,835,008
  unsigned short* ws_q     = (unsigned short*)(ws + 4390912);     // 51,380,224
  unsigned short* ws_k     = (unsigned short*)(ws + 55771136);
  unsigned short* ws_v     = (unsigned short*)(ws + 107151360);
  unsigned short* ws_attn  = (unsigned short*)(ws + 158531584);   // end 209,911,808
  unsigned short* ws_xbf   = ws_attn;  // aliased: xbf dead before attn writes

  hipLaunchKernelGGL(convert_x_kernel, dim3(12544), dim3(256), 0, stream,
                     x, ws_xbf);
  hipLaunchKernelGGL(convert_w_kernel, dim3(3072), dim3(256), 0, stream,
                     qkv_w, proj_w, ws_qkvw, ws_projw);
  hipLaunchKernelGGL(bmprep_kernel, dim3(4480), dim3(256), 0, stream,
                     bias_table, rel_index, mask, ws_biasF, ws_maskF);
  hipLaunchKernelGGL(qkv_gemm_kernel, dim3(392, 6), dim3(512), 0, stream,
                     ws_xbf, ws_qkvw, qkv_b, ws_q, ws_k, ws_v);
  hipLaunchKernelGGL(attn_kernel, dim3(8192), dim3(448), 0, stream,
                     ws_q, ws_k, ws_v, ws_biasF, ws_maskF, ws_attn);
  hipLaunchKernelGGL(proj_gemm_kernel, dim3(392, 2), dim3(512), 0, stream,
                     ws_attn, ws_projw, proj_b, out);
}

// Round 5
// 426.733 us; speedup vs baseline: 1.2270x; 1.0612x over previous
//
#include <hip/hip_runtime.h>
#include <stdint.h>

#define HEADS 16
#define NTOK 98
#define HD 32
#define SCALE_Q 0.17677669529663687f

typedef __attribute__((ext_vector_type(4))) float floatx4;
typedef __attribute__((ext_vector_type(8))) short shortx8;

__device__ __forceinline__ unsigned short f2bf(float f) {
  union { float f; unsigned u; } v; v.f = f;
  unsigned r = v.u + 0x7fffu + ((v.u >> 16) & 1u);
  return (unsigned short)(r >> 16);
}
__device__ __forceinline__ float bf2f(unsigned short s) {
  union { unsigned u; float f; } v; v.u = ((unsigned)s) << 16;
  return v.f;
}

__device__ __forceinline__ void gload_lds16(const void* g, void* l) {
  __builtin_amdgcn_global_load_lds(
      (const __attribute__((address_space(1))) unsigned int*)g,
      (__attribute__((address_space(3))) unsigned int*)l, 16, 0, 0);
}

// ---------------- prep kernels ----------------
__global__ void convert_x_kernel(const float* __restrict__ x,
                                 unsigned short* __restrict__ xbf) {
  int idx = blockIdx.x * 256 + threadIdx.x;  // one per 8 elems; 3,211,264 total
  const float4 f0 = *(const float4*)(x + (size_t)idx * 8);
  const float4 f1 = *(const float4*)(x + (size_t)idx * 8 + 4);
  union { ushort us[8]; uint4 u4; } pk;
  pk.us[0] = f2bf(f0.x); pk.us[1] = f2bf(f0.y);
  pk.us[2] = f2bf(f0.z); pk.us[3] = f2bf(f0.w);
  pk.us[4] = f2bf(f1.x); pk.us[5] = f2bf(f1.y);
  pk.us[6] = f2bf(f1.z); pk.us[7] = f2bf(f1.w);
  *(uint4*)(xbf + (size_t)idx * 8) = pk.u4;
}

__global__ void convert_w_kernel(const float* __restrict__ qkv_w,
                                 const float* __restrict__ proj_w,
                                 unsigned short* __restrict__ wq,
                                 unsigned short* __restrict__ wp) {
  int idx = blockIdx.x * 256 + threadIdx.x;
  if (idx < 1536 * 512) wq[idx] = f2bf(qkv_w[idx]);
  if (idx < 512 * 512) wp[idx] = f2bf(proj_w[idx]);
}

// Separable, fragment-ordered bias/mask tables in BF16 (L2-resident: 2.3 MB):
//   biasF[h][mt][lane][e]  16*7*64*32 shorts = 458,752 B
//   maskF[w][mt][lane][e]  64*7*64*32 shorts = 1,835,008 B
// e = nt*4 + r (padded to 32); i = mt*16 + (lane>>4)*4 + r; j = nt*16 + (lane&15)
// mask pad: j>=98 -> -1e30 (kills softmax); rows i>=98 are discarded at store.
__global__ void bmprep_kernel(const float* __restrict__ table,
                              const int* __restrict__ rel,
                              const float* __restrict__ mask,
                              unsigned short* __restrict__ biasF,
                              unsigned short* __restrict__ maskF) {
  int idx = blockIdx.x * 256 + threadIdx.x;  // 1,146,880 total
  if (idx < 229376) {
    int e = idx & 31, lane = (idx >> 5) & 63;
    int rest = idx >> 11;          // h*7 + mt
    int mt = rest % 7, h = rest / 7;
    int nt = e >> 2, r = e & 3;
    int i = mt * 16 + ((lane >> 4) << 2) + r;
    int j = (nt << 4) + (lane & 15);
    int ii = i < NTOK ? i : 97, jj = j < NTOK ? j : 97;
    float v = (nt < 7) ? table[rel[ii * NTOK + jj] * HEADS + h] : 0.f;
    biasF[idx] = f2bf(v);
  } else {
    int t = idx - 229376;
    int e = t & 31, lane = (t >> 5) & 63;
    int rest = t >> 11;            // w*7 + mt
    int mt = rest % 7, wdx = rest / 7;
    int nt = e >> 2, r = e & 3;
    int i = mt * 16 + ((lane >> 4) << 2) + r;
    int j = (nt << 4) + (lane & 15);
    float v;
    if (nt >= 7) v = 0.f;
    else if (j >= NTOK) v = -1e30f;
    else {
      int ii = i < NTOK ? i : 97;
      v = mask[wdx * (NTOK * NTOK) + ii * NTOK + j];
    }
    maskF[t] = f2bf(v);
  }
}

// ---------------- QKV GEMM: C[50176,1536] = xbf[50176,512] @ qkv_w[1536,512]^T ----------------
// 128x256 tile, BK=32, 512 threads (8 waves, 2x4, each 64x64).
// 1D grid with bijective XCD swizzle: x=id&7, t=id>>3, mb=x*49+t/6, nb=t%6 —
// each XCD walks the 6 n-blocks of each m back-to-back -> A-tile L2-hot.
// 3-buffer pipeline, counted vmcnt(3) (drain-0 only on last iter), one raw
// s_barrier per K-step; seg-XOR swizzle keeps LDS reads conflict-free.
__global__ __launch_bounds__(512, 2)
void qkv_gemm_kernel(const unsigned short* __restrict__ xbf,
                     const unsigned short* __restrict__ wbf,
                     const float* __restrict__ qkv_b,
                     unsigned short* __restrict__ q_out,
                     unsigned short* __restrict__ k_out,
                     unsigned short* __restrict__ v_out) {
  __shared__ unsigned short As[3][128 * 32];
  __shared__ unsigned short Bs[3][256 * 32];
  const int tid = threadIdx.x;
  const int wave = tid >> 6, lane = tid & 63;
  const int id = blockIdx.x;                // 2352 = 8 * (49*6)
  const int xc = id & 7, tt = id >> 3;
  const int m0 = (xc * 49 + tt / 6) * 128, n0 = (tt % 6) * 256;
  const int wm = wave & 1, wn = wave >> 1;
  const int ln15 = lane & 15, qd = lane >> 4;
  const int bl_r = lane >> 2, bl_s = lane & 3;

  const int sg_st = bl_s ^ ((bl_r >> 1) & 3);       // staging source seg
  const int swz_rd = (qd ^ ((ln15 >> 1) & 3)) * 8;  // read seg offset (shorts)

  const unsigned short* aG = xbf + (size_t)(m0 + wave * 16 + bl_r) * 512 + sg_st * 8;
  const unsigned short* bG0 = wbf + (size_t)(n0 + wave * 32 + bl_r) * 512 + sg_st * 8;
  const unsigned short* bG1 = wbf + (size_t)(n0 + wave * 32 + 16 + bl_r) * 512 + sg_st * 8;

#define QSTAGE(bufi, kk)                                                        \
  do {                                                                          \
    gload_lds16((const void*)(aG + (kk)), (void*)&As[bufi][wave * 512]);        \
    gload_lds16((const void*)(bG0 + (kk)), (void*)&Bs[bufi][wave * 1024]);      \
    gload_lds16((const void*)(bG1 + (kk)), (void*)&Bs[bufi][wave * 1024 + 512]);\
  } while (0)

  QSTAGE(0, 0);
  QSTAGE(1, 32);

  floatx4 acc[4][4] = {};
#pragma unroll
  for (int it = 0; it < 16; ++it) {
    if (it == 15) asm volatile("s_waitcnt vmcnt(0)" ::: "memory");
    else          asm volatile("s_waitcnt vmcnt(3)" ::: "memory");
    __builtin_amdgcn_sched_barrier(0);
    __builtin_amdgcn_s_barrier();
    __builtin_amdgcn_sched_barrier(0);
    if (it + 2 < 16) QSTAGE((it + 2) % 3, (it + 2) * 32);
    const unsigned short* Ab = As[it % 3];
    const unsigned short* Bb = Bs[it % 3];
    shortx8 afrag[4], bfrag[4];
#pragma unroll
    for (int mt = 0; mt < 4; ++mt)
      afrag[mt] = *(const shortx8*)&Ab[(wm * 64 + mt * 16 + ln15) * 32 + swz_rd];
#pragma unroll
    for (int nt = 0; nt < 4; ++nt)
      bfrag[nt] = *(const shortx8*)&Bb[(wn * 64 + nt * 16 + ln15) * 32 + swz_rd];
    __builtin_amdgcn_s_setprio(1);
#pragma unroll
    for (int mt = 0; mt < 4; ++mt)
#pragma unroll
      for (int nt = 0; nt < 4; ++nt)
        acc[mt][nt] = __builtin_amdgcn_mfma_f32_16x16x32_bf16(
            afrag[mt], bfrag[nt], acc[mt][nt], 0, 0, 0);
    __builtin_amdgcn_s_setprio(0);
  }
#undef QSTAGE

  // epilogue: + qkv_b, scale q, scatter to [B,H,98,32] bf16.
  // which-output is block-uniform (n0 multiple of 256) -> hoist.
  const int which = n0 >> 9;
  unsigned short* __restrict__ outp =
      (which == 0) ? q_out : ((which == 1) ? k_out : v_out);
  const float sc = (which == 0) ? SCALE_Q : 1.0f;
#pragma unroll
  for (int mt = 0; mt < 4; ++mt) {
#pragma unroll
    for (int r = 0; r < 4; ++r) {
      int grow = m0 + wm * 64 + mt * 16 + qd * 4 + r;
      unsigned b = (unsigned)grow / 98u;
      unsigned i = (unsigned)grow - b * 98u;
#pragma unroll
      for (int nt = 0; nt < 4; ++nt) {
        int col = n0 + wn * 64 + nt * 16 + ln15;
        float val = (acc[mt][nt][r] + qkv_b[col]) * sc;
        int h = (col >> 5) & 15;
        int d = col & 31;
        size_t oidx = ((size_t)(b * 16 + h) * 98 + i) * 32 + d;
        outp[oidx] = f2bf(val);
      }
    }
  }
}

// ---------------- attention: one block per (b,h), 7 waves, one m-tile per wave ----------------
__global__ __launch_bounds__(448, 6)
void attn_kernel(const unsigned short* __restrict__ qg,
                 const unsigned short* __restrict__ kg,
                 const unsigned short* __restrict__ vg,
                 const unsigned short* __restrict__ biasF,
                 const unsigned short* __restrict__ maskF,
                 unsigned short* __restrict__ outg) {
  __shared__ __align__(16) unsigned short Vt[32 * 136];   // 8704 B
  __shared__ __align__(16) unsigned short Ps[7][1928];    // 16 rows x 120 + 8 pad, per wave
  const int tid = threadIdx.x;
  const int bh = blockIdx.x;
  const int b = bh >> 4, h = bh & 15, w = b & 63;
  const size_t base = (size_t)bh * (NTOK * HD);
  const int wave = tid >> 6, lane = tid & 63;   // wave = m-tile (0..6)
  const int ln15 = lane & 15, qd = lane >> 4;

  // zero Vt (pad cols 98..135) and Ps (pad cols 112..119 + tail) — all MFMA
  // slack reads must be finite zeros
  for (int idx = tid; idx < 544; idx += 448)
    ((uint4*)Vt)[idx] = make_uint4(0, 0, 0, 0);
  for (int idx = tid; idx < 1687; idx += 448)
    ((uint4*)Ps)[idx] = make_uint4(0, 0, 0, 0);
  __syncthreads();
  // transpose V into Vt[d][j]; seg-staggered write order spreads the 8-row
  // seg groups across bank quadrants
  for (int t = tid; t < 392; t += 448) {
    int i = t >> 2, seg = t & 3;
    union { uint4 u4; unsigned short us[8]; } u;
    u.u4 = *(const uint4*)(vg + base + i * 32 + seg * 8);
    int d0 = seg * 8;
#pragma unroll
    for (int e0 = 0; e0 < 8; ++e0) {
      int e = (e0 + seg * 2) & 7;
      Vt[(d0 + e) * 136 + i] = u.us[e];
    }
  }
  __syncthreads();

  const int mt = wave;
  // bf16 fragment-ordered bias/mask chunks (L2-resident, 8 x 16B per lane);
  // issued before QK^T so latency hides under the MFMAs
  const shortx8* bB = (const shortx8*)(biasF + (((size_t)h * 7 + mt) * 64 + lane) * 32);
  const shortx8* mB = (const shortx8*)(maskF + (((size_t)w * 7 + mt) * 64 + lane) * 32);
  shortx8 bias_c[4], mask_c[4];
#pragma unroll
  for (int c = 0; c < 4; ++c) { bias_c[c] = bB[c]; mask_c[c] = mB[c]; }

  shortx8 af = *(const shortx8*)(qg + base + (mt * 16 + ln15) * 32 + qd * 8);
  floatx4 sacc[7];
  __builtin_amdgcn_s_setprio(1);
#pragma unroll
  for (int nt = 0; nt < 7; ++nt) {
    shortx8 bf = *(const shortx8*)(kg + base + (nt * 16 + ln15) * 32 + qd * 8);
    floatx4 z = {};
    sacc[nt] = __builtin_amdgcn_mfma_f32_16x16x32_bf16(af, bf, z, 0, 0, 0);
  }
  __builtin_amdgcn_s_setprio(0);
  // add bias+mask (frees the chunks before softmax)
#pragma unroll
  for (int nt = 0; nt < 7; ++nt)
#pragma unroll
    for (int r = 0; r < 4; ++r) {
      int ee = nt * 4 + r, c = ee >> 3, el = ee & 7;
      sacc[nt][r] += bf2f((unsigned short)bias_c[c][el]) +
                     bf2f((unsigned short)mask_c[c][el]);
    }

  float linv[4];
#pragma unroll
  for (int r = 0; r < 4; ++r) {
    float mx = sacc[0][r];
#pragma unroll
    for (int nt = 1; nt < 7; ++nt) mx = fmaxf(mx, sacc[nt][r]);
#pragma unroll
    for (int off = 1; off < 16; off <<= 1)
      mx = fmaxf(mx, __shfl_xor(mx, off, 64));
    float sum = 0.f;
#pragma unroll
    for (int nt = 0; nt < 7; ++nt) {
      float p = __expf(sacc[nt][r] - mx);
      sacc[nt][r] = p;
      sum += p;
    }
#pragma unroll
    for (int off = 1; off < 16; off <<= 1) sum += __shfl_xor(sum, off, 64);
    linv[r] = 1.0f / sum;
  }

  // store full 16x112 P once (stride 120 shorts: 2-way max bank aliasing),
  // then 4 pipelined k-slice MFMAs — no per-slice write->read serialization
  unsigned short* Pw = Ps[wave];
#pragma unroll
  for (int nt = 0; nt < 7; ++nt)
#pragma unroll
    for (int r = 0; r < 4; ++r)
      Pw[(qd * 4 + r) * 120 + nt * 16 + ln15] = f2bf(sacc[nt][r]);

  floatx4 o0 = {}, o1 = {};
  __builtin_amdgcn_s_setprio(1);
#pragma unroll
  for (int ks = 0; ks < 4; ++ks) {
    shortx8 ap = *(const shortx8*)&Pw[ln15 * 120 + ks * 32 + qd * 8];
    shortx8 bv0 = *(const shortx8*)&Vt[ln15 * 136 + ks * 32 + qd * 8];
    shortx8 bv1 = *(const shortx8*)&Vt[(16 + ln15) * 136 + ks * 32 + qd * 8];
    o0 = __builtin_amdgcn_mfma_f32_16x16x32_bf16(ap, bv0, o0, 0, 0, 0);
    o1 = __builtin_amdgcn_mfma_f32_16x16x32_bf16(ap, bv1, o1, 0, 0, 0);
  }
  __builtin_amdgcn_s_setprio(0);
  // store this m-tile to [b*98+i][512] at col h*32
#pragma unroll
  for (int r = 0; r < 4; ++r) {
    int i = mt * 16 + qd * 4 + r;
    if (i < NTOK) {
      size_t ob = ((size_t)b * NTOK + i) * 512 + h * 32;
      outg[ob + ln15] = f2bf(o0[r] * linv[r]);
      outg[ob + 16 + ln15] = f2bf(o1[r] * linv[r]);
    }
  }
}

// ---------------- proj GEMM: out[50176,512] = attn[50176,512] @ proj_w[512,512]^T + b ----------------
// 128x128 tile, 256 threads (4 waves 2x2, each 64x64), 3 blocks/CU (48 KB LDS)
// -> grid 1568 = 2.04 occupancy rounds (was 1.53: ~33% tail waste).
// Same 3-buffer counted-vmcnt pipeline (4 loads/stage -> vmcnt(4)) + swizzles.
__global__ __launch_bounds__(256, 3)
void proj_gemm_kernel(const unsigned short* __restrict__ a,
                      const unsigned short* __restrict__ wbf,
                      const float* __restrict__ proj_b,
                      float* __restrict__ out) {
  __shared__ unsigned short As[3][128 * 32];
  __shared__ unsigned short Bs[3][128 * 32];
  const int tid = threadIdx.x;
  const int wave = tid >> 6, lane = tid & 63;
  const int id = blockIdx.x;                // 1568 = 8 * (49*4)
  const int xc = id & 7, tt = id >> 3;
  const int m0 = (xc * 49 + (tt >> 2)) * 128, n0 = (tt & 3) * 128;
  const int wm = wave & 1, wn = wave >> 1;
  const int ln15 = lane & 15, qd = lane >> 4;
  const int bl_r = lane >> 2, bl_s = lane & 3;

  const int sg_st = bl_s ^ ((bl_r >> 1) & 3);
  const int swz_rd = (qd ^ ((ln15 >> 1) & 3)) * 8;

  const unsigned short* aG0 = a + (size_t)(m0 + wave * 32 + bl_r) * 512 + sg_st * 8;
  const unsigned short* aG1 = aG0 + (size_t)16 * 512;
  const unsigned short* bG0 = wbf + (size_t)(n0 + wave * 32 + bl_r) * 512 + sg_st * 8;
  const unsigned short* bG1 = bG0 + (size_t)16 * 512;

#define PSTAGE(bufi, kk)                                                         \
  do {                                                                           \
    gload_lds16((const void*)(aG0 + (kk)), (void*)&As[bufi][wave * 1024]);       \
    gload_lds16((const void*)(aG1 + (kk)), (void*)&As[bufi][wave * 1024 + 512]); \
    gload_lds16((const void*)(bG0 + (kk)), (void*)&Bs[bufi][wave * 1024]);       \
    gload_lds16((const void*)(bG1 + (kk)), (void*)&Bs[bufi][wave * 1024 + 512]); \
  } while (0)

  PSTAGE(0, 0);
  PSTAGE(1, 32);

  floatx4 acc[4][4] = {};
#pragma unroll
  for (int it = 0; it < 16; ++it) {
    if (it == 15) asm volatile("s_waitcnt vmcnt(0)" ::: "memory");
    else          asm volatile("s_waitcnt vmcnt(4)" ::: "memory");
    __builtin_amdgcn_sched_barrier(0);
    __builtin_amdgcn_s_barrier();
    __builtin_amdgcn_sched_barrier(0);
    if (it + 2 < 16) PSTAGE((it + 2) % 3, (it + 2) * 32);
    const unsigned short* Ab = As[it % 3];
    const unsigned short* Bb = Bs[it % 3];
    shortx8 afrag[4], bfrag[4];
#pragma unroll
    for (int mt = 0; mt < 4; ++mt)
      afrag[mt] = *(const shortx8*)&Ab[(wm * 64 + mt * 16 + ln15) * 32 + swz_rd];
#pragma unroll
    for (int nt = 0; nt < 4; ++nt)
      bfrag[nt] = *(const shortx8*)&Bb[(wn * 64 + nt * 16 + ln15) * 32 + swz_rd];
    __builtin_amdgcn_s_setprio(1);
#pragma unroll
    for (int mt = 0; mt < 4; ++mt)
#pragma unroll
      for (int nt = 0; nt < 4; ++nt)
        acc[mt][nt] = __builtin_amdgcn_mfma_f32_16x16x32_bf16(
            afrag[mt], bfrag[nt], acc[mt][nt], 0, 0, 0);
    __builtin_amdgcn_s_setprio(0);
  }
#undef PSTAGE

#pragma unroll
  for (int mt = 0; mt < 4; ++mt) {
#pragma unroll
    for (int r = 0; r < 4; ++r) {
      int grow = m0 + wm * 64 + mt * 16 + qd * 4 + r;
#pragma unroll
      for (int nt = 0; nt < 4; ++nt) {
        int col = n0 + wn * 64 + nt * 16 + ln15;
        out[(size_t)grow * 512 + col] = acc[mt][nt][r] + proj_b[col];
      }
    }
  }
}

// ---------------- launch ----------------
extern "C" void kernel_launch(void* const* d_in, const int* in_sizes, int n_in,
                              void* d_out, int out_size, void* d_ws, size_t ws_size,
                              hipStream_t stream) {
  const float* x          = (const float*)d_in[0];
  const float* mask       = (const float*)d_in[1];
  const float* qkv_w      = (const float*)d_in[2];
  const float* qkv_b      = (const float*)d_in[3];
  const float* proj_w     = (const float*)d_in[4];
  const float* proj_b     = (const float*)d_in[5];
  const float* bias_table = (const float*)d_in[6];
  const int*   rel_index  = (const int*)d_in[7];
  float* out = (float*)d_out;

  char* ws = (char*)d_ws;
  unsigned short* ws_qkvw  = (unsigned short*)(ws + 0);           // 1,572,864
  unsigned short* ws_projw = (unsigned short*)(ws + 1572864);     //   524,288
  unsigned short* ws_biasF = (unsigned short*)(ws + 2097152);     //   458,752
  unsigned short* ws_maskF = (unsigned short*)(ws + 2555904);     // 1,835,008
  unsigned short* ws_q     = (unsigned short*)(ws + 4390912);     // 51,380,224
  unsigned short* ws_k     = (unsigned short*)(ws + 55771136);
  unsigned short* ws_v     = (unsigned short*)(ws + 107151360);
  unsigned short* ws_attn  = (unsigned short*)(ws + 158531584);   // end 209,911,808
  unsigned short* ws_xbf   = ws_attn;  // aliased: xbf dead before attn writes

  hipLaunchKernelGGL(convert_x_kernel, dim3(12544), dim3(256), 0, stream,
                     x, ws_xbf);
  hipLaunchKernelGGL(convert_w_kernel, dim3(3072), dim3(256), 0, stream,
                     qkv_w, proj_w, ws_qkvw, ws_projw);
  hipLaunchKernelGGL(bmprep_kernel, dim3(4480), dim3(256), 0, stream,
                     bias_table, rel_index, mask, ws_biasF, ws_maskF);
  hipLaunchKernelGGL(qkv_gemm_kernel, dim3(2352), dim3(512), 0, stream,
                     ws_xbf, ws_qkvw, qkv_b, ws_q, ws_k, ws_v);
  hipLaunchKernelGGL(attn_kernel, dim3(8192), dim3(448), 0, stream,
                     ws_q, ws_k, ws_v, ws_biasF, ws_maskF, ws_attn);
  hipLaunchKernelGGL(proj_gemm_kernel, dim3(1568), dim3(256), 0, stream,
                     ws_attn, ws_projw, proj_b, out);
}